// Round 4
// baseline (262.639 us; speedup 1.0000x reference)
//
#include <hip/hip_runtime.h>
#include <math.h>

#define KTOP 20
#define RPB 128   // rows per copy_sims block

// native vector type accepted by __builtin_nontemporal_{load,store}
typedef float vfloat4 __attribute__((ext_vector_type(4)));

// ---------------------------------------------------------------------------
// Kernel 1: normalized query row per batch -> ws.  grid(B), block(64).
// ---------------------------------------------------------------------------
__global__ __launch_bounds__(64) void qnorm_kernel(
    const float* __restrict__ x, const int* __restrict__ qrels,
    float* __restrict__ qn, int R)
{
    int b = blockIdx.x;
    int t = threadIdx.x;                 // 0..63 == d
    int qr = qrels[b];
    float v = x[((long)b * R + qr) * 64 + t];
    float ss = v * v;
#pragma unroll
    for (int m = 1; m < 64; m <<= 1) ss += __shfl_xor(ss, m, 64);
    qn[b * 64 + t] = v / fmaxf(sqrtf(ss), 1e-12f);
}

// ---------------------------------------------------------------------------
// Kernel 2: the HBM pass.  Copy x -> out (nontemporal), per-row cosine sim
// and L2-norm denominator -> ws.  16-lane group per row, float4 per lane.
// grid(R/RPB, B), block(256) -> 4096 blocks = 16/CU: latency hidden by TLP.
// ---------------------------------------------------------------------------
__global__ __launch_bounds__(256) void copy_sims_kernel(
    const float* __restrict__ x, const int* __restrict__ qrels,
    const float* __restrict__ qn, float* __restrict__ out,
    float* __restrict__ sims, float* __restrict__ dnorm, int R)
{
    const int b = blockIdx.y;
    const int t = threadIdx.x;             // 0..255
    const int grp = t >> 4, l16 = t & 15;  // 16 groups of 16 lanes
    const int qr = qrels[b];
    const vfloat4 q4 = *(const vfloat4*)(qn + b * 64 + l16 * 4);
    const long xbase = (long)b * R * 64;
    const int row0 = blockIdx.x * RPB;

#pragma unroll
    for (int i = 0; i < RPB / 16; ++i) {
        int row = row0 + i * 16 + grp;
        long base = xbase + (long)row * 64 + l16 * 4;
        const vfloat4 v = __builtin_nontemporal_load((const vfloat4*)(x + base));
        __builtin_nontemporal_store(v, (vfloat4*)(out + base));
        float dot = v.x * q4.x + v.y * q4.y + v.z * q4.z + v.w * q4.w;
        float ss  = v.x * v.x + v.y * v.y + v.z * v.z + v.w * v.w;
#pragma unroll
        for (int m = 1; m < 16; m <<= 1) {  // stays inside the 16-lane group
            dot += __shfl_xor(dot, m, 64);
            ss  += __shfl_xor(ss,  m, 64);
        }
        if (l16 == 0) {
            float dn = fmaxf(sqrtf(ss), 1e-12f);
            sims[(long)b * R + row]  = (row == qr) ? -1.0f : dot / dn;
            dnorm[(long)b * R + row] = dn;
        }
    }
}

// ---------------------------------------------------------------------------
// Kernel 3: selection + weighting + query-row write.  ONE wave per batch.
// All R sims register-resident (32/lane); entries <= threshold -> -inf;
// iterative butterfly argmax (JAX tie-break: value desc, index asc) with
// early exit once the max is -inf.  Weighting is order-invariant over the
// valid set, so no sorting beyond argmax order is needed.
// grid(B), block(64).
// ---------------------------------------------------------------------------
__global__ __launch_bounds__(64) void select_kernel(
    const float* __restrict__ x, const int* __restrict__ qrels,
    const float* __restrict__ sims, const float* __restrict__ dnorm,
    const float* __restrict__ thr_raw, const float* __restrict__ str_raw,
    const float* __restrict__ wscale_p, const float* __restrict__ temp_p,
    float* __restrict__ out, int R)
{
    __shared__ float s_topv[KTOP];
    __shared__ int   s_topi[KTOP];
    __shared__ float s_adj[KTOP];
    __shared__ float s_strength;

    const int b = blockIdx.x;
    const int t = threadIdx.x;             // 0..63
    const float threshold = 1.0f / (1.0f + expf(-thr_raw[0]));

    // load all sims into registers, pre-threshold (self row is -1 < threshold)
    float lv[32]; int li[32];
#pragma unroll
    for (int j = 0; j < 32; ++j) {
        int r = t + 64 * j;
        if (r < R) {
            float s = sims[(long)b * R + r];
            lv[j] = (s > threshold) ? s : -INFINITY;
            li[j] = r;
        } else { lv[j] = -INFINITY; li[j] = 0x7fffffff; }
    }

    // iterative argmax with early exit
    int ksel = 0;
    for (int k = 0; k < KTOP; ++k) {
        float bv = -INFINITY; int bi = 0x7fffffff;
#pragma unroll
        for (int j = 0; j < 32; ++j) {
            // per-lane indices increase with j: strict > keeps smallest index
            if (lv[j] > bv) { bv = lv[j]; bi = li[j]; }
        }
#pragma unroll
        for (int m = 1; m < 64; m <<= 1) {
            float v2 = __shfl_xor(bv, m, 64);
            int   i2 = __shfl_xor(bi, m, 64);
            if (v2 > bv || (v2 == bv && i2 < bi)) { bv = v2; bi = i2; }
        }
        if (bv == -INFINITY) break;        // candidates exhausted
        if (t == 0) { s_topv[k] = bv; s_topi[k] = bi; }
        ++ksel;
#pragma unroll
        for (int j = 0; j < 32; ++j) if (li[j] == bi) lv[j] = -INFINITY;
    }
    __syncthreads();

    // scalar weighting on lane 0 (every selected entry is valid by construction)
    if (t == 0 && ksel > 0) {
        float temp = fminf(fmaxf(temp_p[0], 0.1f), 10.0f);
        float wsc  = wscale_p[0];
        float m = -INFINITY;
        for (int k = 0; k < ksel; ++k) m = fmaxf(m, s_topv[k] / temp);
        float w[KTOP]; float wsum = 0.0f;
        for (int k = 0; k < ksel; ++k) { w[k] = expf(s_topv[k] / temp - m); wsum += w[k]; }
        float adj[KTOP]; float asum = 0.0f;
        for (int k = 0; k < ksel; ++k) {
            float tv = s_topv[k];
            float sw = 1.0f / (1.0f + expf(-(tv - threshold) * 10.0f));
            float a  = (w[k] / wsum) * sw * (1.0f + wsc * tv);
            adj[k] = a; asum += a;
        }
        for (int k = 0; k < ksel; ++k)
            s_adj[k] = (adj[k] / (asum + 1e-8f)) / dnorm[(long)b * R + s_topi[k]];
        s_strength = (1.0f / (1.0f + expf(-str_raw[0]))) * 0.2f;
    }
    __syncthreads();

    // gather + mix + write query row (64 lanes, one dim each)
    if (ksel > 0) {
        const int qr = qrels[b];
        long qb = ((long)b * R + qr) * 64 + t;
        float qo = x[qb];
        float acc = 0.0f;
        for (int k = 0; k < ksel; ++k)
            acc += s_adj[k] * x[((long)b * R + s_topi[k]) * 64 + t];
        float st = s_strength;
        out[qb] = (1.0f - st) * qo + st * acc;
    }
    // ksel==0: copy_sims already wrote the original row -> matches reference
}

// ---------------------------------------------------------------------------
extern "C" void kernel_launch(void* const* d_in, const int* in_sizes, int n_in,
                              void* d_out, int out_size, void* d_ws, size_t ws_size,
                              hipStream_t stream) {
    const float* x      = (const float*)d_in[0];
    const int*   qrels  = (const int*)d_in[1];
    const float* thr    = (const float*)d_in[2];
    const float* str    = (const float*)d_in[3];
    const float* wscale = (const float*)d_in[4];
    const float* temp   = (const float*)d_in[5];
    float* out = (float*)d_out;

    const int B = in_sizes[1];
    const int D = 64;
    const int R = in_sizes[0] / (B * D);
    (void)D; (void)ws_size;

    // ws layout (floats): qn[B*64] | sims[B*R] | dnorm[B*R]
    float* qn    = (float*)d_ws;
    float* sims  = qn + (size_t)B * 64;
    float* dnorm = sims + (size_t)B * R;

    qnorm_kernel<<<B, 64, 0, stream>>>(x, qrels, qn, R);

    dim3 grid2(R / RPB, B);
    copy_sims_kernel<<<grid2, 256, 0, stream>>>(x, qrels, qn, out, sims, dnorm, R);

    select_kernel<<<B, 64, 0, stream>>>(x, qrels, sims, dnorm,
                                        thr, str, wscale, temp, out, R);
}